// Round 12
// baseline (329.171 us; speedup 1.0000x reference)
//
#include <hip/hip_runtime.h>

// ---------------- constants ----------------
#define BB   512   // batch
#define SS   256   // seq len
#define EE   128   // emb dim
#define HH   128   // per-dir hidden
#define LL   59    // labels
#define STARTL 57
#define STOPL  58
#define VOCAB 50000

typedef float  f32x4  __attribute__((ext_vector_type(4)));
typedef short  bf16x8 __attribute__((ext_vector_type(8)));
typedef short  s16x4  __attribute__((ext_vector_type(4)));

__device__ __forceinline__ short f2bf(float f) {
    unsigned u = __float_as_uint(f);
    u += 0x7FFFu + ((u >> 16) & 1u);   // RNE
    return (short)(u >> 16);
}
__device__ __forceinline__ float bf2f(unsigned short s) {
    return __uint_as_float(((unsigned)s) << 16);
}
__device__ __forceinline__ float sigf(float x) {
    float e = __builtin_amdgcn_exp2f(-1.44269504f * x);
    return __builtin_amdgcn_rcpf(1.0f + e);
}
__device__ __forceinline__ float tanhf_(float x) {
    float e = __builtin_amdgcn_exp2f(2.88539008f * x);
    return 1.0f - 2.0f * __builtin_amdgcn_rcpf(e + 1.0f);
}
__device__ __forceinline__ float wmax64(float v) {
    #pragma unroll
    for (int o = 32; o; o >>= 1) v = fmaxf(v, __shfl_xor(v, o));
    return v;
}
__device__ __forceinline__ float wsum64(float v) {
    #pragma unroll
    for (int o = 32; o; o >>= 1) v += __shfl_xor(v, o);
    return v;
}
__device__ __forceinline__ float rlane(float v, int i) {
    return __uint_as_float(__builtin_amdgcn_readlane(__float_as_uint(v), i));
}
// LDS-only barrier: global ops stay in flight across it.
__device__ __forceinline__ void bar_lds() {
    asm volatile("s_waitcnt lgkmcnt(0)\n\ts_barrier" ::: "memory");
}

// ---------------- kernel 0: f32 -> bf16 tables + bias sums ----------------
__global__ __launch_bounds__(256) void conv_k(
    const float* __restrict__ embed,
    const float* __restrict__ Wih_f, const float* __restrict__ Wih_b,
    const float* __restrict__ Whh_f, const float* __restrict__ Whh_b,
    const float* __restrict__ bih_f, const float* __restrict__ bhh_f,
    const float* __restrict__ bih_b, const float* __restrict__ bhh_b,
    unsigned short* __restrict__ ebf, unsigned short* __restrict__ wix,
    unsigned short* __restrict__ whb, float* __restrict__ bsum)
{
    const int W1 = VOCAB * EE / 4;      // embed float4
    const int W2 = W1 + 2 * 16384;      // wix  (Wih both dirs)
    const int W3 = W2 + 2 * 16384;      // whb  (Whh both dirs)
    const int W4 = W3 + 1024;           // bias sums
    for (int i = blockIdx.x * blockDim.x + threadIdx.x; i < W4;
         i += gridDim.x * blockDim.x) {
        if (i < W1) {
            float4 v = ((const float4*)embed)[i];
            s16x4 s = { f2bf(v.x), f2bf(v.y), f2bf(v.z), f2bf(v.w) };
            ((s16x4*)ebf)[i] = s;
        } else if (i < W2) {
            const int j = i - W1, d = j >> 14, e = j & 16383;
            float4 v = ((const float4*)(d ? Wih_b : Wih_f))[e];
            s16x4 s = { f2bf(v.x), f2bf(v.y), f2bf(v.z), f2bf(v.w) };
            ((s16x4*)wix)[d * 16384 + e] = s;
        } else if (i < W3) {
            const int j = i - W2, d = j >> 14, e = j & 16383;
            float4 v = ((const float4*)(d ? Whh_b : Whh_f))[e];
            s16x4 s = { f2bf(v.x), f2bf(v.y), f2bf(v.z), f2bf(v.w) };
            ((s16x4*)whb)[d * 16384 + e] = s;
        } else {
            const int m = i - W3, d = m >> 9, c = m & 511;
            bsum[d * 512 + c] = d ? (bih_b[c] + bhh_b[c]) : (bih_f[c] + bhh_f[c]);
        }
    }
}

// ---------------- kernel 1: fused BiLSTM (wave-specialized, R11 — unchanged) ----------------
__global__ __launch_bounds__(512, 2) void lstm_f(
    const int* __restrict__ x, const unsigned short* __restrict__ ebf,
    const unsigned short* __restrict__ wix, const unsigned short* __restrict__ whb,
    const float* __restrict__ bsum,
    const float* __restrict__ h0, const float* __restrict__ c0,
    const float* __restrict__ Wout,
    unsigned short* __restrict__ fpF, unsigned short* __restrict__ fpB)
{
    const int tid = threadIdx.x;
    const int w = tid >> 6, l = tid & 63, qd = l >> 4, n = l & 15;
    const int rt = blockIdx.x & 127, dir = blockIdx.x >> 7;
    const int b0 = rt * 4;
    unsigned short* fp = dir ? fpB : fpF;

    __shared__ __align__(16) short hbuf[2][2048];     // [ts&1][tile-row 0..15][8]; pads stay 0
    __shared__ __align__(16) float gxb[2][4][2048];   // [group&1][tau][slot][batch][gate] f32
    __shared__ int xsh[4 * 256];                      // [j 0..3][t]

    // zero both hbuf buffers + stage x tile
    #pragma unroll
    for (int i = 0; i < 2; ++i) ((s16x4*)hbuf)[tid + i * 512] = (s16x4)0;
    #pragma unroll
    for (int i = 0; i < 2; ++i) {
        const int k = tid + i * 512;
        xsh[k] = x[(size_t)(b0 + (k >> 8)) * SS + (k & 255)];
    }

    if (w < 4) {
        // ---------- h-wave: slots 2w, 2w+1 (recurrence only) ----------
        const int s0 = 2 * w, s1 = 2 * w + 1;
        bf16x8 fh0[4][4], fh1[4][4];
        #pragma unroll
        for (int g = 0; g < 4; ++g) {
            #pragma unroll
            for (int kk = 0; kk < 4; ++kk) {
                fh0[g][kk] = *(const bf16x8*)(whb + dir * 65536
                             + (size_t)(g * 128 + 16 * s0 + n) * 128 + kk * 32 + qd * 8);
                fh1[g][kk] = *(const bf16x8*)(whb + dir * 65536
                             + (size_t)(g * 128 + 16 * s1 + n) * 128 + kk * 32 + qd * 8);
            }
        }
        float cst0 = c0[((size_t)dir * BB + b0 + qd) * HH + 16 * s0 + n];
        float cst1 = c0[((size_t)dir * BB + b0 + qd) * HH + 16 * s1 + n];

        __syncthreads();   // B1: zeros + xsh visible
        {   // h0 -> hbuf[0] tile-rows {0,4,8,12} (512 thr = 4 rows x 128 cols)
            const int j = tid >> 7, c = tid & 127;
            hbuf[0][((c >> 3) * 16 + 4 * j) * 8 + (c & 7)] =
                f2bf(h0[((size_t)dir * BB + b0 + j) * HH + c]);
        }
        __syncthreads();   // B2: hbuf[0] + gxb[group 0] ready

        __builtin_amdgcn_s_setprio(1);   // h-waves carry the serial chain

        const int hid0 = 16 * s0 + n, hc0 = hid0 >> 3, ho0 = hid0 & 7;
        const int hid1 = 16 * s1 + n, hc1 = hid1 >> 3, ho1 = hid1 & 7;
        const int gs0 = (s0 * 64 + qd * 16 + n) * 4;
        const int gs1 = (s1 * 64 + qd * 16 + n) * 4;

        // persistent accumulators: elements 1..3 correspond to zero-padded
        // hbuf rows -> they stay 0 forever; only element 0 is read.
        f32x4 a0[4], a1[4];
        #pragma unroll
        for (int g = 0; g < 4; ++g) {
            a0[g] = (f32x4){0.f, 0.f, 0.f, 0.f};
            a1[g] = (f32x4){0.f, 0.f, 0.f, 0.f};
        }

        for (int ts = 0; ts < SS; ++ts) {
            const int cur = ts & 1, nxt = cur ^ 1;
            const int gbuf = (ts >> 2) & 1, tau = ts & 3;

            const f32x4 g0 = *(const f32x4*)&gxb[gbuf][tau][gs0];
            const f32x4 g1 = *(const f32x4*)&gxb[gbuf][tau][gs1];

            bf16x8 ah[4];
            #pragma unroll
            for (int kk = 0; kk < 4; ++kk)
                ah[kk] = *(const bf16x8*)&hbuf[cur][((kk * 4 + qd) * 16 + n) * 8];

            a0[0][0] = g0[0]; a0[1][0] = g0[1]; a0[2][0] = g0[2]; a0[3][0] = g0[3];
            a1[0][0] = g1[0]; a1[1][0] = g1[1]; a1[2][0] = g1[2]; a1[3][0] = g1[3];

            // slot0 MFMAs first ...
            #pragma unroll
            for (int kk = 0; kk < 4; ++kk) {
                #pragma unroll
                for (int g = 0; g < 4; ++g)
                    a0[g] = __builtin_amdgcn_mfma_f32_16x16x32_bf16(ah[kk], fh0[g][kk], a0[g], 0, 0, 0);
            }
            {   // ... slot0 gates overlap slot1 MFMA issue
                const float iv0 = sigf(a0[0][0]), fv0 = sigf(a0[1][0]);
                const float gv0 = tanhf_(a0[2][0]), ov0 = sigf(a0[3][0]);
                const float cc0 = fv0 * cst0 + iv0 * gv0;
                cst0 = cc0;
                hbuf[nxt][(hc0 * 16 + 4 * qd) * 8 + ho0] = f2bf(ov0 * tanhf_(cc0));
            }
            #pragma unroll
            for (int kk = 0; kk < 4; ++kk) {
                #pragma unroll
                for (int g = 0; g < 4; ++g)
                    a1[g] = __builtin_amdgcn_mfma_f32_16x16x32_bf16(ah[kk], fh1[g][kk], a1[g], 0, 0, 0);
            }
            {   // slot1 gates: the only tail on the barrier
                const float iv1 = sigf(a1[0][0]), fv1 = sigf(a1[1][0]);
                const float gv1 = tanhf_(a1[2][0]), ov1 = sigf(a1[3][0]);
                const float cc1 = fv1 * cst1 + iv1 * gv1;
                cst1 = cc1;
                hbuf[nxt][(hc1 * 16 + 4 * qd) * 8 + ho1] = f2bf(ov1 * tanhf_(cc1));
            }
            bar_lds();
        }
    } else {
        // ---------- x-wave: gx kk-split over 4 intervals + per-interval proj ----------
        const int ct = w - 4;             // proj col-tile: labels 16ct..16ct+15
        const int s0 = 2 * (w - 4), s1 = s0 + 1;
        bf16x8 fx0[4][4], fx1[4][4]; float bs0[4], bs1[4];
        #pragma unroll
        for (int g = 0; g < 4; ++g) {
            bs0[g] = bsum[dir * 512 + g * 128 + 16 * s0 + n];
            bs1[g] = bsum[dir * 512 + g * 128 + 16 * s1 + n];
            #pragma unroll
            for (int kk = 0; kk < 4; ++kk) {
                fx0[g][kk] = *(const bf16x8*)(wix + dir * 65536
                             + (size_t)(g * 128 + 16 * s0 + n) * 128 + kk * 32 + qd * 8);
                fx1[g][kk] = *(const bf16x8*)(wix + dir * 65536
                             + (size_t)(g * 128 + 16 * s1 + n) * 128 + kk * 32 + qd * 8);
            }
        }
        bf16x8 wbx[4];   // Wout fragments for col-tile ct (zero-padded >= LL)
        {
            const int col = ct * 16 + n;
            #pragma unroll
            for (int kk = 0; kk < 4; ++kk) {
                bf16x8 v = (bf16x8)0;
                if (col < LL) {
                    const float* p = Wout + (size_t)col * 256 + dir * 128 + kk * 32 + qd * 8;
                    #pragma unroll
                    for (int j = 0; j < 8; ++j) v[j] = f2bf(p[j]);
                }
                wbx[kk] = v;
            }
        }
        const int gs0 = (s0 * 64 + qd * 16 + n) * 4;
        const int gs1 = (s1 * 64 + qd * 16 + n) * 4;
        const int jb   = n >> 2;          // A row n -> batch j = n>>2
        const int tau  = n & 3;           //           tau = n&3
        const int jrow = jb * 256;

        // emission pointer: walks h_0, h_1, ... -> tep dir0: 0..SS-1, dir1: SS-1..0
        unsigned short* fpx = fp + ((size_t)(b0 + qd) * SS + (dir ? SS - 1 : 0)) * 64
                            + ct * 16 + n;
        const ptrdiff_t fpd = dir ? -64 : 64;

        // e <- emb frags for A rows of group G (lane's row = (jb, 4G+tau))
        auto loadfrag = [&](int G, bf16x8* e) {
            const int t  = 4 * G + tau;
            const int te = dir ? (SS - 1 - t) : t;
            const int xi = xsh[jrow + te];
            const unsigned short* er = ebf + (size_t)xi * EE + qd * 8;
            e[0] = *(const bf16x8*)(er);
            e[1] = *(const bf16x8*)(er + 32);
            e[2] = *(const bf16x8*)(er + 64);
            e[3] = *(const bf16x8*)(er + 96);
        };
        auto gxStore = [&](const f32x4* c, const float* bs, int gsv, int buf) {
            #pragma unroll
            for (int r = 0; r < 4; ++r) {
                f32x4 p = { c[0][r] + bs[0], c[1][r] + bs[1],
                            c[2][r] + bs[2], c[3][r] + bs[3] };
                *(f32x4*)&gxb[buf][r][gsv] = p;
            }
        };
        // project h_{ts-1} (lives in hbuf[ts&1], stable during interval ts);
        // read pattern identical to h-wave ah reads -> conflict-free.
        auto projx = [&](int ts) {
            f32x4 pp = (f32x4){0.f, 0.f, 0.f, 0.f};
            #pragma unroll
            for (int kk = 0; kk < 4; ++kk) {
                const bf16x8 a = *(const bf16x8*)&hbuf[ts & 1][((kk * 4 + qd) * 16 + n) * 8];
                pp = __builtin_amdgcn_mfma_f32_16x16x32_bf16(a, wbx[kk], pp, 0, 0, 0);
            }
            *fpx = (unsigned short)f2bf(pp[0]);
            fpx += fpd;
        };

        __syncthreads();   // B1: xsh visible
        bf16x8 eA[4], eB[4];
        loadfrag(0, eA);                       // group 0 frags
        {   // pre-loop: gxb[0] <- group 0, both slots (one-time stall)
            f32x4 c[4] = { {0,0,0,0}, {0,0,0,0}, {0,0,0,0}, {0,0,0,0} };
            #pragma unroll
            for (int g = 0; g < 4; ++g)
                #pragma unroll
                for (int kk = 0; kk < 4; ++kk)
                    c[g] = __builtin_amdgcn_mfma_f32_16x16x32_bf16(eA[kk], fx0[g][kk], c[g], 0, 0, 0);
            gxStore(c, bs0, gs0, 0);
            #pragma unroll
            for (int g = 0; g < 4; ++g) c[g] = (f32x4){0.f, 0.f, 0.f, 0.f};
            #pragma unroll
            for (int g = 0; g < 4; ++g)
                #pragma unroll
                for (int kk = 0; kk < 4; ++kk)
                    c[g] = __builtin_amdgcn_mfma_f32_16x16x32_bf16(eA[kk], fx1[g][kk], c[g], 0, 0, 0);
            gxStore(c, bs1, gs1, 0);
        }
        loadfrag(1, eB);                       // group 1 frags
        __syncthreads();   // B2

        // Group G (intervals ts=4G..4G+3): produce gx group G+1 spread evenly
        // (I0: slot0 kk01 | I1: slot0 kk23+store | I2: slot1 kk01 |
        //  I3: slot1 kk23+store), prefetch frags G+2 (I0), project h_{ts-1}
        // every interval. Per-interval: 8 gx + 4 proj = 12 MFMA.
        auto xgroup = [&](int G, bf16x8* use, bf16x8* pre) {
            const int t0 = 4 * G;
            const bool prod = (G + 1 < SS / 4);
            const int  nb   = (G + 1) & 1;
            f32x4 c[4];
            // ---- I0 ----
            if (G + 2 < SS / 4) loadfrag(G + 2, pre);
            if (prod) {
                #pragma unroll
                for (int g = 0; g < 4; ++g) c[g] = (f32x4){0.f, 0.f, 0.f, 0.f};
                #pragma unroll
                for (int kk = 0; kk < 2; ++kk)
                    #pragma unroll
                    for (int g = 0; g < 4; ++g)
                        c[g] = __builtin_amdgcn_mfma_f32_16x16x32_bf16(use[kk], fx0[g][kk], c[g], 0, 0, 0);
            }
            if (t0 > 0) projx(t0);
            bar_lds();
            // ---- I1 ----
            if (prod) {
                #pragma unroll
                for (int kk = 2; kk < 4; ++kk)
                    #pragma unroll
                    for (int g = 0; g < 4; ++g)
                        c[g] = __builtin_amdgcn_mfma_f32_16x16x32_bf16(use[kk], fx0[g][kk], c[g], 0, 0, 0);
                gxStore(c, bs0, gs0, nb);
            }
            projx(t0 + 1);
            bar_lds();
            // ---- I2 ----
            if (prod) {
                #pragma unroll
                for (int g = 0; g < 4; ++g) c[g] = (f32x4){0.f, 0.f, 0.f, 0.f};
                #pragma unroll
                for (int kk = 0; kk < 2; ++kk)
                    #pragma unroll
                    for (int g = 0; g < 4; ++g)
                        c[g] = __builtin_amdgcn_mfma_f32_16x16x32_bf16(use[kk], fx1[g][kk], c[g], 0, 0, 0);
            }
            projx(t0 + 2);
            bar_lds();
            // ---- I3 ----
            if (prod) {
                #pragma unroll
                for (int kk = 2; kk < 4; ++kk)
                    #pragma unroll
                    for (int g = 0; g < 4; ++g)
                        c[g] = __builtin_amdgcn_mfma_f32_16x16x32_bf16(use[kk], fx1[g][kk], c[g], 0, 0, 0);
                gxStore(c, bs1, gs1, nb);
            }
            projx(t0 + 3);
            bar_lds();
        };
        for (int G = 0; G < SS / 4; G += 2) {
            xgroup(G,     eB, eA);
            xgroup(G + 1, eA, eB);
        }
        projx(SS);   // h_{SS-1} (hbuf[0], SS even)
    }
}

// ---------------- kernel 2: CRF fwd/bwd split + gold + reduce (R12) ----------------
// R12 changes vs R11:
//  (a) per-step dot via LDS broadcast (R6's lsedot, now measured in
//      isolation): ds_write ea, 15x broadcast ds_read_b128 (same addr all
//      lanes = conflict-free), 59 pure-VGPR fmacs. Same d_k accumulation
//      order as the readlane form -> bit-identical.
//  (b) the 512-way same-address atomicAdd replaced by per-block partial
//      stores + agent-scope counter; last block reduces 512 partials and
//      writes out once. Removes the serialized cross-XCD atomic tail.
__global__ __launch_bounds__(128, 1) void crf_k(
    const unsigned short* __restrict__ fpF, const unsigned short* __restrict__ fpB,
    const float* __restrict__ bout, const int* __restrict__ y,
    const float* __restrict__ trans, float* __restrict__ part,
    unsigned* __restrict__ cnt, float* __restrict__ out)
{
    const int tid = threadIdx.x;
    const int wv = tid >> 6;          // 0 = alpha wave, 1 = beta+gold wave
    const int j = tid & 63;
    const int b = blockIdx.x;
    const size_t bS = (size_t)b * SS;
    const bool valid = (j < LL);
    const int  jr = valid ? j : (LL - 1);
    const float L2E = 1.44269504f, LN2 = 0.69314718f;

    __shared__ __align__(16) float eash[2][64];
    __shared__ float exch[64];
    __shared__ float gshare;

    float etr[LL];
    #pragma unroll
    for (int i = 0; i < LL; ++i) {
        const float t = wv ? trans[i * LL + jr] : trans[jr * LL + i];
        etr[i] = valid ? __builtin_amdgcn_exp2f(t * L2E) : 0.0f;
    }
    const float bo = valid ? bout[jr] : 0.0f;

    float st;
    if (wv == 0) st = valid ? ((j == STARTL) ? 0.0f : -10000.0f * L2E) : -1e30f;
    else         st = valid ? trans[STOPL * LL + jr] * L2E : -1e30f;
    float Kn = 0.0f;   // lagged stabilizer

    float* myea = &eash[wv][0];

    // LDS-broadcast dot: d_k += etr[i] * ea[i], i === k (mod 8); identical
    // accumulation order to the readlane form.
    auto lsedot = [&](float ex) {
        myea[j] = ex;                       // ds_write; lgkm wait auto-inserted
        f32x4 e4[15];
        #pragma unroll
        for (int q = 0; q < 15; ++q) e4[q] = *(const f32x4*)(myea + 4 * q);
        float d0 = 0.f, d1 = 0.f, d2 = 0.f, d3 = 0.f;
        float d4 = 0.f, d5 = 0.f, d6 = 0.f, d7 = 0.f;
        #pragma unroll
        for (int i = 0; i < 56; i += 8) {
            d0 += etr[i]     * e4[(i    ) >> 2][(i    ) & 3];
            d1 += etr[i + 1] * e4[(i + 1) >> 2][(i + 1) & 3];
            d2 += etr[i + 2] * e4[(i + 2) >> 2][(i + 2) & 3];
            d3 += etr[i + 3] * e4[(i + 3) >> 2][(i + 3) & 3];
            d4 += etr[i + 4] * e4[(i + 4) >> 2][(i + 4) & 3];
            d5 += etr[i + 5] * e4[(i + 5) >> 2][(i + 5) & 3];
            d6 += etr[i + 6] * e4[(i + 6) >> 2][(i + 6) & 3];
            d7 += etr[i + 7] * e4[(i + 7) >> 2][(i + 7) & 3];
        }
        d0 += etr[56] * e4[14][0];
        d1 += etr[57] * e4[14][1];
        d2 += etr[58] * e4[14][2];
        return ((d0 + d1) + (d2 + d3)) + ((d4 + d5) + (d6 + d7));
    };

    auto tAt = [&](int u) { return wv ? (SS - 1 - u) : u; };

    float fF[8], fB[8];
    #pragma unroll
    for (int q = 0; q < 8; ++q) {
        const int t = tAt(q);
        fF[q] = bf2f(fpF[(bS + t) * 64 + j]);
        fB[q] = bf2f(fpB[(bS + t) * 64 + j]);
    }

    for (int u0 = 0; u0 < SS / 2; u0 += 8) {
        float nF[8], nB[8];
        #pragma unroll
        for (int q = 0; q < 8; ++q) { nF[q] = 0.0f; nB[q] = 0.0f; }
        if (u0 + 8 < SS / 2) {
            #pragma unroll
            for (int q = 0; q < 8; ++q) {
                const int t = tAt(u0 + 8 + q);
                nF[q] = bf2f(fpF[(bS + t) * 64 + j]);
                nB[q] = bf2f(fpB[(bS + t) * 64 + j]);
            }
        }
        float fs[8];
        #pragma unroll
        for (int q = 0; q < 8; ++q) fs[q] = (fF[q] + fB[q] + bo) * L2E;

        #pragma unroll
        for (int u = 0; u < 8; ++u) {
            if (wv == 0) {
                // alpha[j] <- fs[j] + LSE_i(alpha[i] + T[j,i])
                const float Kc = Kn;
                const float ea = __builtin_amdgcn_exp2f(st - Kc);
                Kn = fmaxf(rlane(st, 1), rlane(st, STARTL));
                const float dot = lsedot(ea);
                st = fs[u] + Kc + __builtin_amdgcn_logf(dot);   // v_log_f32 = log2
            } else {
                // beta[i] <- LSE_j( (fs[j] + beta[j]) + T[j,i] )
                const float g = fs[u] + st;
                const float Kc = Kn;
                const float eg = __builtin_amdgcn_exp2f(g - Kc);
                Kn = rlane(g, 1);
                const float dot = lsedot(eg);
                st = Kc + __builtin_amdgcn_logf(dot);
            }
        }
        #pragma unroll
        for (int q = 0; q < 8; ++q) { fF[q] = nF[q]; fB[q] = nB[q]; }
    }

    if (wv == 1) {
        // gold path score (whole 0..255 range, 64 lanes x 4)
        float g = 0.0f;
        #pragma unroll
        for (int q = 0; q < 4; ++q) {
            const int t  = q * 64 + j;
            const int yt = y[bS + t];
            const int yp = t ? y[bS + t - 1] : STARTL;
            g += bf2f(fpF[(bS + t) * 64 + yt]) + bf2f(fpB[(bS + t) * 64 + yt])
               + bout[yt] + trans[yt * LL + yp];
        }
        g = wsum64(g);
        if (j == 0) {
            g += trans[STOPL * LL + y[bS + SS - 1]];
            gshare = g;
        }
        exch[j] = st;      // beta_127 (log2)
    }
    __syncthreads();
    if (wv == 0) {
        // fwd = LN2 * LSE2_i(alpha_127[i] + beta_127[i])
        const float v2 = valid ? (st + exch[j]) : -1e30f;
        const float m2 = wmax64(v2);
        const float s  = wsum64(__builtin_amdgcn_exp2f(v2 - m2));
        const float fwd = LN2 * (m2 + __builtin_amdgcn_logf(s));

        int last = 0;
        if (j == 0) {
            __hip_atomic_store(part + b, fwd - gshare, __ATOMIC_RELEASE,
                               __HIP_MEMORY_SCOPE_AGENT);
            const unsigned old = __hip_atomic_fetch_add(cnt, 1u, __ATOMIC_ACQ_REL,
                                                        __HIP_MEMORY_SCOPE_AGENT);
            last = (old == BB - 1);
        }
        last = __shfl(last, 0);
        if (last) {   // final block: reduce 512 partials, single write
            float s2 = 0.0f;
            #pragma unroll
            for (int q = 0; q < 8; ++q)
                s2 += __hip_atomic_load(part + q * 64 + j, __ATOMIC_RELAXED,
                                        __HIP_MEMORY_SCOPE_AGENT);
            s2 = wsum64(s2);
            if (j == 0) out[0] = s2;
        }
    }
}

// ---------------- launcher ----------------
extern "C" void kernel_launch(void* const* d_in, const int* in_sizes, int n_in,
                              void* d_out, int out_size, void* d_ws, size_t ws_size,
                              hipStream_t stream)
{
    (void)in_sizes; (void)n_in; (void)out_size; (void)ws_size;
    const int*   x      = (const int*)  d_in[0];
    const int*   y      = (const int*)  d_in[1];
    const float* embed  = (const float*)d_in[2];
    const float* Wih_f  = (const float*)d_in[3];
    const float* Whh_f  = (const float*)d_in[4];
    const float* bih_f  = (const float*)d_in[5];
    const float* bhh_f  = (const float*)d_in[6];
    const float* Wih_b  = (const float*)d_in[7];
    const float* Whh_b  = (const float*)d_in[8];
    const float* bih_b  = (const float*)d_in[9];
    const float* bhh_b  = (const float*)d_in[10];
    const float* Wout   = (const float*)d_in[11];
    const float* bout   = (const float*)d_in[12];
    const float* trans  = (const float*)d_in[13];
    const float* h0     = (const float*)d_in[14];
    const float* c0     = (const float*)d_in[15];

    const size_t MiB = 1ull << 20;
    unsigned short* fpF  = (unsigned short*)d_ws;                                   // 16 MiB
    unsigned short* fpB  = (unsigned short*)((char*)d_ws + 16 * MiB);               // 16 MiB
    unsigned short* ebf  = (unsigned short*)((char*)d_ws + 32 * MiB);               // 12.8 MB
    unsigned short* wix  = (unsigned short*)((char*)d_ws + 45 * MiB);               // 256 KiB
    unsigned short* whb  = (unsigned short*)((char*)d_ws + 45 * MiB + 256 * 1024);  // 256 KiB
    float*          bsum = (float*)((char*)d_ws + 45 * MiB + 512 * 1024);           // 4 KiB
    float*          part = (float*)((char*)d_ws + 46 * MiB);                        // 2 KiB
    unsigned*       cnt  = (unsigned*)((char*)d_ws + 46 * MiB + 4096);              // 4 B

    hipMemsetAsync(d_out, 0, sizeof(float), stream);
    hipMemsetAsync(cnt, 0, sizeof(unsigned), stream);
    conv_k<<<2048, 256, 0, stream>>>(embed, Wih_f, Wih_b, Whh_f, Whh_b,
                                     bih_f, bhh_f, bih_b, bhh_b,
                                     ebf, wix, whb, bsum);
    lstm_f<<<256, 512, 0, stream>>>(x, ebf, wix, whb, bsum, h0, c0, Wout,
                                    fpF, fpB);
    crf_k<<<BB, 128, 0, stream>>>(fpF, fpB, bout, y, trans, part, cnt,
                                  (float*)d_out);
}

// Round 13
// 323.739 us; speedup vs baseline: 1.0168x; 1.0168x over previous
//
#include <hip/hip_runtime.h>

// ---------------- constants ----------------
#define BB   512   // batch
#define SS   256   // seq len
#define EE   128   // emb dim
#define HH   128   // per-dir hidden
#define LL   59    // labels
#define STARTL 57
#define STOPL  58
#define VOCAB 50000

typedef float  f32x4  __attribute__((ext_vector_type(4)));
typedef short  bf16x8 __attribute__((ext_vector_type(8)));
typedef short  s16x4  __attribute__((ext_vector_type(4)));

__device__ __forceinline__ short f2bf(float f) {
    unsigned u = __float_as_uint(f);
    u += 0x7FFFu + ((u >> 16) & 1u);   // RNE
    return (short)(u >> 16);
}
__device__ __forceinline__ float bf2f(unsigned short s) {
    return __uint_as_float(((unsigned)s) << 16);
}
__device__ __forceinline__ float sigf(float x) {
    float e = __builtin_amdgcn_exp2f(-1.44269504f * x);
    return __builtin_amdgcn_rcpf(1.0f + e);
}
__device__ __forceinline__ float tanhf_(float x) {
    float e = __builtin_amdgcn_exp2f(2.88539008f * x);
    return 1.0f - 2.0f * __builtin_amdgcn_rcpf(e + 1.0f);
}
__device__ __forceinline__ float wmax64(float v) {
    #pragma unroll
    for (int o = 32; o; o >>= 1) v = fmaxf(v, __shfl_xor(v, o));
    return v;
}
__device__ __forceinline__ float wsum64(float v) {
    #pragma unroll
    for (int o = 32; o; o >>= 1) v += __shfl_xor(v, o);
    return v;
}
__device__ __forceinline__ float rlane(float v, int i) {
    return __uint_as_float(__builtin_amdgcn_readlane(__float_as_uint(v), i));
}
// LDS-only barrier: global ops stay in flight across it.
__device__ __forceinline__ void bar_lds() {
    asm volatile("s_waitcnt lgkmcnt(0)\n\ts_barrier" ::: "memory");
}

// ---------------- kernel 0: f32 -> bf16 tables + bias sums ----------------
__global__ __launch_bounds__(256) void conv_k(
    const float* __restrict__ embed,
    const float* __restrict__ Wih_f, const float* __restrict__ Wih_b,
    const float* __restrict__ Whh_f, const float* __restrict__ Whh_b,
    const float* __restrict__ bih_f, const float* __restrict__ bhh_f,
    const float* __restrict__ bih_b, const float* __restrict__ bhh_b,
    unsigned short* __restrict__ ebf, unsigned short* __restrict__ wix,
    unsigned short* __restrict__ whb, float* __restrict__ bsum)
{
    const int W1 = VOCAB * EE / 4;      // embed float4
    const int W2 = W1 + 2 * 16384;      // wix  (Wih both dirs)
    const int W3 = W2 + 2 * 16384;      // whb  (Whh both dirs)
    const int W4 = W3 + 1024;           // bias sums
    for (int i = blockIdx.x * blockDim.x + threadIdx.x; i < W4;
         i += gridDim.x * blockDim.x) {
        if (i < W1) {
            float4 v = ((const float4*)embed)[i];
            s16x4 s = { f2bf(v.x), f2bf(v.y), f2bf(v.z), f2bf(v.w) };
            ((s16x4*)ebf)[i] = s;
        } else if (i < W2) {
            const int j = i - W1, d = j >> 14, e = j & 16383;
            float4 v = ((const float4*)(d ? Wih_b : Wih_f))[e];
            s16x4 s = { f2bf(v.x), f2bf(v.y), f2bf(v.z), f2bf(v.w) };
            ((s16x4*)wix)[d * 16384 + e] = s;
        } else if (i < W3) {
            const int j = i - W2, d = j >> 14, e = j & 16383;
            float4 v = ((const float4*)(d ? Whh_b : Whh_f))[e];
            s16x4 s = { f2bf(v.x), f2bf(v.y), f2bf(v.z), f2bf(v.w) };
            ((s16x4*)whb)[d * 16384 + e] = s;
        } else {
            const int m = i - W3, d = m >> 9, c = m & 511;
            bsum[d * 512 + c] = d ? (bih_b[c] + bhh_b[c]) : (bih_f[c] + bhh_f[c]);
        }
    }
}

// ---------------- kernel 1: fused BiLSTM (wave-specialized, R11 final) ----------------
// Final structure after 12 rounds:
//  - 256 blocks (128 row-tiles x 2 dirs), 512 thr = 8 waves (4 h + 4 x).
//  - x-waves batch 4 timesteps per gx MFMA burst (all 16 M-rows real),
//    kk-split evenly over the 4 barrier intervals; they also carry the
//    Wout projection (1 proj MFMA chain per interval, conflict-free reads)
//    and depth-2 embedding register prefetch.
//  - h-waves: slot0 MFMAs -> slot0 gates (overlap slot1 MFMA issue) ->
//    slot1 MFMAs -> slot1 gates; s_setprio(1); lgkm-only barrier.
//  Measured: 174.8 us, MfmaUtil 45%, no spills. Occupancy-invariant
//  (R3), histogram-flat (R10), single-slot gate tail (R11).
__global__ __launch_bounds__(512, 2) void lstm_f(
    const int* __restrict__ x, const unsigned short* __restrict__ ebf,
    const unsigned short* __restrict__ wix, const unsigned short* __restrict__ whb,
    const float* __restrict__ bsum,
    const float* __restrict__ h0, const float* __restrict__ c0,
    const float* __restrict__ Wout,
    unsigned short* __restrict__ fpF, unsigned short* __restrict__ fpB)
{
    const int tid = threadIdx.x;
    const int w = tid >> 6, l = tid & 63, qd = l >> 4, n = l & 15;
    const int rt = blockIdx.x & 127, dir = blockIdx.x >> 7;
    const int b0 = rt * 4;
    unsigned short* fp = dir ? fpB : fpF;

    __shared__ __align__(16) short hbuf[2][2048];     // [ts&1][tile-row 0..15][8]; pads stay 0
    __shared__ __align__(16) float gxb[2][4][2048];   // [group&1][tau][slot][batch][gate] f32
    __shared__ int xsh[4 * 256];                      // [j 0..3][t]

    // zero both hbuf buffers + stage x tile
    #pragma unroll
    for (int i = 0; i < 2; ++i) ((s16x4*)hbuf)[tid + i * 512] = (s16x4)0;
    #pragma unroll
    for (int i = 0; i < 2; ++i) {
        const int k = tid + i * 512;
        xsh[k] = x[(size_t)(b0 + (k >> 8)) * SS + (k & 255)];
    }

    if (w < 4) {
        // ---------- h-wave: slots 2w, 2w+1 (recurrence only) ----------
        const int s0 = 2 * w, s1 = 2 * w + 1;
        bf16x8 fh0[4][4], fh1[4][4];
        #pragma unroll
        for (int g = 0; g < 4; ++g) {
            #pragma unroll
            for (int kk = 0; kk < 4; ++kk) {
                fh0[g][kk] = *(const bf16x8*)(whb + dir * 65536
                             + (size_t)(g * 128 + 16 * s0 + n) * 128 + kk * 32 + qd * 8);
                fh1[g][kk] = *(const bf16x8*)(whb + dir * 65536
                             + (size_t)(g * 128 + 16 * s1 + n) * 128 + kk * 32 + qd * 8);
            }
        }
        float cst0 = c0[((size_t)dir * BB + b0 + qd) * HH + 16 * s0 + n];
        float cst1 = c0[((size_t)dir * BB + b0 + qd) * HH + 16 * s1 + n];

        __syncthreads();   // B1: zeros + xsh visible
        {   // h0 -> hbuf[0] tile-rows {0,4,8,12} (512 thr = 4 rows x 128 cols)
            const int j = tid >> 7, c = tid & 127;
            hbuf[0][((c >> 3) * 16 + 4 * j) * 8 + (c & 7)] =
                f2bf(h0[((size_t)dir * BB + b0 + j) * HH + c]);
        }
        __syncthreads();   // B2: hbuf[0] + gxb[group 0] ready

        __builtin_amdgcn_s_setprio(1);   // h-waves carry the serial chain

        const int hid0 = 16 * s0 + n, hc0 = hid0 >> 3, ho0 = hid0 & 7;
        const int hid1 = 16 * s1 + n, hc1 = hid1 >> 3, ho1 = hid1 & 7;
        const int gs0 = (s0 * 64 + qd * 16 + n) * 4;
        const int gs1 = (s1 * 64 + qd * 16 + n) * 4;

        // persistent accumulators: elements 1..3 correspond to zero-padded
        // hbuf rows -> they stay 0 forever; only element 0 is read.
        f32x4 a0[4], a1[4];
        #pragma unroll
        for (int g = 0; g < 4; ++g) {
            a0[g] = (f32x4){0.f, 0.f, 0.f, 0.f};
            a1[g] = (f32x4){0.f, 0.f, 0.f, 0.f};
        }

        for (int ts = 0; ts < SS; ++ts) {
            const int cur = ts & 1, nxt = cur ^ 1;
            const int gbuf = (ts >> 2) & 1, tau = ts & 3;

            const f32x4 g0 = *(const f32x4*)&gxb[gbuf][tau][gs0];
            const f32x4 g1 = *(const f32x4*)&gxb[gbuf][tau][gs1];

            bf16x8 ah[4];
            #pragma unroll
            for (int kk = 0; kk < 4; ++kk)
                ah[kk] = *(const bf16x8*)&hbuf[cur][((kk * 4 + qd) * 16 + n) * 8];

            a0[0][0] = g0[0]; a0[1][0] = g0[1]; a0[2][0] = g0[2]; a0[3][0] = g0[3];
            a1[0][0] = g1[0]; a1[1][0] = g1[1]; a1[2][0] = g1[2]; a1[3][0] = g1[3];

            // slot0 MFMAs first ...
            #pragma unroll
            for (int kk = 0; kk < 4; ++kk) {
                #pragma unroll
                for (int g = 0; g < 4; ++g)
                    a0[g] = __builtin_amdgcn_mfma_f32_16x16x32_bf16(ah[kk], fh0[g][kk], a0[g], 0, 0, 0);
            }
            {   // ... slot0 gates overlap slot1 MFMA issue
                const float iv0 = sigf(a0[0][0]), fv0 = sigf(a0[1][0]);
                const float gv0 = tanhf_(a0[2][0]), ov0 = sigf(a0[3][0]);
                const float cc0 = fv0 * cst0 + iv0 * gv0;
                cst0 = cc0;
                hbuf[nxt][(hc0 * 16 + 4 * qd) * 8 + ho0] = f2bf(ov0 * tanhf_(cc0));
            }
            #pragma unroll
            for (int kk = 0; kk < 4; ++kk) {
                #pragma unroll
                for (int g = 0; g < 4; ++g)
                    a1[g] = __builtin_amdgcn_mfma_f32_16x16x32_bf16(ah[kk], fh1[g][kk], a1[g], 0, 0, 0);
            }
            {   // slot1 gates: the only tail on the barrier
                const float iv1 = sigf(a1[0][0]), fv1 = sigf(a1[1][0]);
                const float gv1 = tanhf_(a1[2][0]), ov1 = sigf(a1[3][0]);
                const float cc1 = fv1 * cst1 + iv1 * gv1;
                cst1 = cc1;
                hbuf[nxt][(hc1 * 16 + 4 * qd) * 8 + ho1] = f2bf(ov1 * tanhf_(cc1));
            }
            bar_lds();
        }
    } else {
        // ---------- x-wave: gx kk-split over 4 intervals + per-interval proj ----------
        const int ct = w - 4;             // proj col-tile: labels 16ct..16ct+15
        const int s0 = 2 * (w - 4), s1 = s0 + 1;
        bf16x8 fx0[4][4], fx1[4][4]; float bs0[4], bs1[4];
        #pragma unroll
        for (int g = 0; g < 4; ++g) {
            bs0[g] = bsum[dir * 512 + g * 128 + 16 * s0 + n];
            bs1[g] = bsum[dir * 512 + g * 128 + 16 * s1 + n];
            #pragma unroll
            for (int kk = 0; kk < 4; ++kk) {
                fx0[g][kk] = *(const bf16x8*)(wix + dir * 65536
                             + (size_t)(g * 128 + 16 * s0 + n) * 128 + kk * 32 + qd * 8);
                fx1[g][kk] = *(const bf16x8*)(wix + dir * 65536
                             + (size_t)(g * 128 + 16 * s1 + n) * 128 + kk * 32 + qd * 8);
            }
        }
        bf16x8 wbx[4];   // Wout fragments for col-tile ct (zero-padded >= LL)
        {
            const int col = ct * 16 + n;
            #pragma unroll
            for (int kk = 0; kk < 4; ++kk) {
                bf16x8 v = (bf16x8)0;
                if (col < LL) {
                    const float* p = Wout + (size_t)col * 256 + dir * 128 + kk * 32 + qd * 8;
                    #pragma unroll
                    for (int j = 0; j < 8; ++j) v[j] = f2bf(p[j]);
                }
                wbx[kk] = v;
            }
        }
        const int gs0 = (s0 * 64 + qd * 16 + n) * 4;
        const int gs1 = (s1 * 64 + qd * 16 + n) * 4;
        const int jb   = n >> 2;          // A row n -> batch j = n>>2
        const int tau  = n & 3;           //           tau = n&3
        const int jrow = jb * 256;

        // emission pointer: walks h_0, h_1, ... -> tep dir0: 0..SS-1, dir1: SS-1..0
        unsigned short* fpx = fp + ((size_t)(b0 + qd) * SS + (dir ? SS - 1 : 0)) * 64
                            + ct * 16 + n;
        const ptrdiff_t fpd = dir ? -64 : 64;

        // e <- emb frags for A rows of group G (lane's row = (jb, 4G+tau))
        auto loadfrag = [&](int G, bf16x8* e) {
            const int t  = 4 * G + tau;
            const int te = dir ? (SS - 1 - t) : t;
            const int xi = xsh[jrow + te];
            const unsigned short* er = ebf + (size_t)xi * EE + qd * 8;
            e[0] = *(const bf16x8*)(er);
            e[1] = *(const bf16x8*)(er + 32);
            e[2] = *(const bf16x8*)(er + 64);
            e[3] = *(const bf16x8*)(er + 96);
        };
        auto gxStore = [&](const f32x4* c, const float* bs, int gsv, int buf) {
            #pragma unroll
            for (int r = 0; r < 4; ++r) {
                f32x4 p = { c[0][r] + bs[0], c[1][r] + bs[1],
                            c[2][r] + bs[2], c[3][r] + bs[3] };
                *(f32x4*)&gxb[buf][r][gsv] = p;
            }
        };
        // project h_{ts-1} (lives in hbuf[ts&1], stable during interval ts);
        // read pattern identical to h-wave ah reads -> conflict-free.
        auto projx = [&](int ts) {
            f32x4 pp = (f32x4){0.f, 0.f, 0.f, 0.f};
            #pragma unroll
            for (int kk = 0; kk < 4; ++kk) {
                const bf16x8 a = *(const bf16x8*)&hbuf[ts & 1][((kk * 4 + qd) * 16 + n) * 8];
                pp = __builtin_amdgcn_mfma_f32_16x16x32_bf16(a, wbx[kk], pp, 0, 0, 0);
            }
            *fpx = (unsigned short)f2bf(pp[0]);
            fpx += fpd;
        };

        __syncthreads();   // B1: xsh visible
        bf16x8 eA[4], eB[4];
        loadfrag(0, eA);                       // group 0 frags
        {   // pre-loop: gxb[0] <- group 0, both slots (one-time stall)
            f32x4 c[4] = { {0,0,0,0}, {0,0,0,0}, {0,0,0,0}, {0,0,0,0} };
            #pragma unroll
            for (int g = 0; g < 4; ++g)
                #pragma unroll
                for (int kk = 0; kk < 4; ++kk)
                    c[g] = __builtin_amdgcn_mfma_f32_16x16x32_bf16(eA[kk], fx0[g][kk], c[g], 0, 0, 0);
            gxStore(c, bs0, gs0, 0);
            #pragma unroll
            for (int g = 0; g < 4; ++g) c[g] = (f32x4){0.f, 0.f, 0.f, 0.f};
            #pragma unroll
            for (int g = 0; g < 4; ++g)
                #pragma unroll
                for (int kk = 0; kk < 4; ++kk)
                    c[g] = __builtin_amdgcn_mfma_f32_16x16x32_bf16(eA[kk], fx1[g][kk], c[g], 0, 0, 0);
            gxStore(c, bs1, gs1, 0);
        }
        loadfrag(1, eB);                       // group 1 frags
        __syncthreads();   // B2

        // Group G (intervals ts=4G..4G+3): produce gx group G+1 spread evenly
        // (I0: slot0 kk01 | I1: slot0 kk23+store | I2: slot1 kk01 |
        //  I3: slot1 kk23+store), prefetch frags G+2 (I0), project h_{ts-1}
        // every interval. Per-interval: 8 gx + 4 proj = 12 MFMA.
        auto xgroup = [&](int G, bf16x8* use, bf16x8* pre) {
            const int t0 = 4 * G;
            const bool prod = (G + 1 < SS / 4);
            const int  nb   = (G + 1) & 1;
            f32x4 c[4];
            // ---- I0 ----
            if (G + 2 < SS / 4) loadfrag(G + 2, pre);
            if (prod) {
                #pragma unroll
                for (int g = 0; g < 4; ++g) c[g] = (f32x4){0.f, 0.f, 0.f, 0.f};
                #pragma unroll
                for (int kk = 0; kk < 2; ++kk)
                    #pragma unroll
                    for (int g = 0; g < 4; ++g)
                        c[g] = __builtin_amdgcn_mfma_f32_16x16x32_bf16(use[kk], fx0[g][kk], c[g], 0, 0, 0);
            }
            if (t0 > 0) projx(t0);
            bar_lds();
            // ---- I1 ----
            if (prod) {
                #pragma unroll
                for (int kk = 2; kk < 4; ++kk)
                    #pragma unroll
                    for (int g = 0; g < 4; ++g)
                        c[g] = __builtin_amdgcn_mfma_f32_16x16x32_bf16(use[kk], fx0[g][kk], c[g], 0, 0, 0);
                gxStore(c, bs0, gs0, nb);
            }
            projx(t0 + 1);
            bar_lds();
            // ---- I2 ----
            if (prod) {
                #pragma unroll
                for (int g = 0; g < 4; ++g) c[g] = (f32x4){0.f, 0.f, 0.f, 0.f};
                #pragma unroll
                for (int kk = 0; kk < 2; ++kk)
                    #pragma unroll
                    for (int g = 0; g < 4; ++g)
                        c[g] = __builtin_amdgcn_mfma_f32_16x16x32_bf16(use[kk], fx1[g][kk], c[g], 0, 0, 0);
            }
            projx(t0 + 2);
            bar_lds();
            // ---- I3 ----
            if (prod) {
                #pragma unroll
                for (int kk = 2; kk < 4; ++kk)
                    #pragma unroll
                    for (int g = 0; g < 4; ++g)
                        c[g] = __builtin_amdgcn_mfma_f32_16x16x32_bf16(use[kk], fx1[g][kk], c[g], 0, 0, 0);
                gxStore(c, bs1, gs1, nb);
            }
            projx(t0 + 3);
            bar_lds();
        };
        for (int G = 0; G < SS / 4; G += 2) {
            xgroup(G,     eB, eA);
            xgroup(G + 1, eA, eB);
        }
        projx(SS);   // h_{SS-1} (hbuf[0], SS even)
    }
}

// ---------------- kernel 2: CRF fwd/bwd split + gold + reduce (R5/R11 final) ----------------
// Wave 0: alpha over t=0..127; wave 1: beta (transposed trans) over t=255..128
// + gold. fwd = LSE_i(alpha_127 + beta_127). 1024 waves = 1/SIMD machine-wide.
// Lagged stabilizer + log2 domain + 8-way dot accumulators. R12 showed the
// LDS-broadcast dot and atomic-tail removal are null — this is the scan's
// serial-chain floor.
__global__ __launch_bounds__(128, 1) void crf_k(
    const unsigned short* __restrict__ fpF, const unsigned short* __restrict__ fpB,
    const float* __restrict__ bout, const int* __restrict__ y,
    const float* __restrict__ trans, float* __restrict__ out)
{
    const int tid = threadIdx.x;
    const int wv = tid >> 6;          // 0 = alpha wave, 1 = beta+gold wave
    const int j = tid & 63;
    const int b = blockIdx.x;
    const size_t bS = (size_t)b * SS;
    const bool valid = (j < LL);
    const int  jr = valid ? j : (LL - 1);
    const float L2E = 1.44269504f, LN2 = 0.69314718f;

    __shared__ float exch[64];
    __shared__ float gshare;

    float etr[LL];
    #pragma unroll
    for (int i = 0; i < LL; ++i) {
        const float t = wv ? trans[i * LL + jr] : trans[jr * LL + i];
        etr[i] = valid ? __builtin_amdgcn_exp2f(t * L2E) : 0.0f;
    }
    const float bo = valid ? bout[jr] : 0.0f;

    float st;
    if (wv == 0) st = valid ? ((j == STARTL) ? 0.0f : -10000.0f * L2E) : -1e30f;
    else         st = valid ? trans[STOPL * LL + jr] * L2E : -1e30f;
    float Kn = 0.0f;   // lagged stabilizer

    auto tAt = [&](int u) { return wv ? (SS - 1 - u) : u; };

    float fF[8], fB[8];
    #pragma unroll
    for (int q = 0; q < 8; ++q) {
        const int t = tAt(q);
        fF[q] = bf2f(fpF[(bS + t) * 64 + j]);
        fB[q] = bf2f(fpB[(bS + t) * 64 + j]);
    }

    for (int u0 = 0; u0 < SS / 2; u0 += 8) {
        float nF[8], nB[8];
        #pragma unroll
        for (int q = 0; q < 8; ++q) { nF[q] = 0.0f; nB[q] = 0.0f; }
        if (u0 + 8 < SS / 2) {
            #pragma unroll
            for (int q = 0; q < 8; ++q) {
                const int t = tAt(u0 + 8 + q);
                nF[q] = bf2f(fpF[(bS + t) * 64 + j]);
                nB[q] = bf2f(fpB[(bS + t) * 64 + j]);
            }
        }
        float fs[8];
        #pragma unroll
        for (int q = 0; q < 8; ++q) fs[q] = (fF[q] + fB[q] + bo) * L2E;

        #pragma unroll
        for (int u = 0; u < 8; ++u) {
            if (wv == 0) {
                const float Kc = Kn;
                const float ea = __builtin_amdgcn_exp2f(st - Kc);
                Kn = fmaxf(rlane(st, 1), rlane(st, STARTL));
                float d0 = 0.f, d1 = 0.f, d2 = 0.f, d3 = 0.f;
                float d4 = 0.f, d5 = 0.f, d6 = 0.f, d7 = 0.f;
                #pragma unroll
                for (int i = 0; i < 56; i += 8) {
                    d0 += etr[i]     * rlane(ea, i);
                    d1 += etr[i + 1] * rlane(ea, i + 1);
                    d2 += etr[i + 2] * rlane(ea, i + 2);
                    d3 += etr[i + 3] * rlane(ea, i + 3);
                    d4 += etr[i + 4] * rlane(ea, i + 4);
                    d5 += etr[i + 5] * rlane(ea, i + 5);
                    d6 += etr[i + 6] * rlane(ea, i + 6);
                    d7 += etr[i + 7] * rlane(ea, i + 7);
                }
                d0 += etr[56] * rlane(ea, 56);
                d1 += etr[57] * rlane(ea, 57);
                d2 += etr[58] * rlane(ea, 58);
                const float dot = ((d0 + d1) + (d2 + d3)) + ((d4 + d5) + (d6 + d7));
                st = fs[u] + Kc + __builtin_amdgcn_logf(dot);   // v_log_f32 = log2
            } else {
                const float g = fs[u] + st;
                const float Kc = Kn;
                const float eg = __builtin_amdgcn_exp2f(g - Kc);
                Kn = rlane(g, 1);
                float d0 = 0.f, d1 = 0.f, d2 = 0.f, d3 = 0.f;
                float d4 = 0.f, d5 = 0.f, d6 = 0.f, d7 = 0.f;
                #pragma unroll
                for (int i = 0; i < 56; i += 8) {
                    d0 += etr[i]     * rlane(eg, i);
                    d1 += etr[i + 1] * rlane(eg, i + 1);
                    d2 += etr[i + 2] * rlane(eg, i + 2);
                    d3 += etr[i + 3] * rlane(eg, i + 3);
                    d4 += etr[i + 4] * rlane(eg, i + 4);
                    d5 += etr[i + 5] * rlane(eg, i + 5);
                    d6 += etr[i + 6] * rlane(eg, i + 6);
                    d7 += etr[i + 7] * rlane(eg, i + 7);
                }
                d0 += etr[56] * rlane(eg, 56);
                d1 += etr[57] * rlane(eg, 57);
                d2 += etr[58] * rlane(eg, 58);
                const float dot = ((d0 + d1) + (d2 + d3)) + ((d4 + d5) + (d6 + d7));
                st = Kc + __builtin_amdgcn_logf(dot);
            }
        }
        #pragma unroll
        for (int q = 0; q < 8; ++q) { fF[q] = nF[q]; fB[q] = nB[q]; }
    }

    if (wv == 1) {
        float g = 0.0f;
        #pragma unroll
        for (int q = 0; q < 4; ++q) {
            const int t  = q * 64 + j;
            const int yt = y[bS + t];
            const int yp = t ? y[bS + t - 1] : STARTL;
            g += bf2f(fpF[(bS + t) * 64 + yt]) + bf2f(fpB[(bS + t) * 64 + yt])
               + bout[yt] + trans[yt * LL + yp];
        }
        g = wsum64(g);
        if (j == 0) {
            g += trans[STOPL * LL + y[bS + SS - 1]];
            gshare = g;
        }
        exch[j] = st;      // beta_127 (log2)
    }
    __syncthreads();
    if (wv == 0) {
        const float v2 = valid ? (st + exch[j]) : -1e30f;
        const float m2 = wmax64(v2);
        const float s  = wsum64(__builtin_amdgcn_exp2f(v2 - m2));
        const float fwd = LN2 * (m2 + __builtin_amdgcn_logf(s));
        if (j == 0) atomicAdd(out, fwd - gshare);
    }
}

// ---------------- launcher ----------------
extern "C" void kernel_launch(void* const* d_in, const int* in_sizes, int n_in,
                              void* d_out, int out_size, void* d_ws, size_t ws_size,
                              hipStream_t stream)
{
    (void)in_sizes; (void)n_in; (void)out_size; (void)ws_size;
    const int*   x      = (const int*)  d_in[0];
    const int*   y      = (const int*)  d_in[1];
    const float* embed  = (const float*)d_in[2];
    const float* Wih_f  = (const float*)d_in[3];
    const float* Whh_f  = (const float*)d_in[4];
    const float* bih_f  = (const float*)d_in[5];
    const float* bhh_f  = (const float*)d_in[6];
    const float* Wih_b  = (const float*)d_in[7];
    const float* Whh_b  = (const float*)d_in[8];
    const float* bih_b  = (const float*)d_in[9];
    const float* bhh_b  = (const float*)d_in[10];
    const float* Wout   = (const float*)d_in[11];
    const float* bout   = (const float*)d_in[12];
    const float* trans  = (const float*)d_in[13];
    const float* h0     = (const float*)d_in[14];
    const float* c0     = (const float*)d_in[15];

    const size_t MiB = 1ull << 20;
    unsigned short* fpF  = (unsigned short*)d_ws;                                   // 16 MiB
    unsigned short* fpB  = (unsigned short*)((char*)d_ws + 16 * MiB);               // 16 MiB
    unsigned short* ebf  = (unsigned short*)((char*)d_ws + 32 * MiB);               // 12.8 MB
    unsigned short* wix  = (unsigned short*)((char*)d_ws + 45 * MiB);               // 256 KiB
    unsigned short* whb  = (unsigned short*)((char*)d_ws + 45 * MiB + 256 * 1024);  // 256 KiB
    float*          bsum = (float*)((char*)d_ws + 45 * MiB + 512 * 1024);           // 4 KiB

    hipMemsetAsync(d_out, 0, sizeof(float), stream);
    conv_k<<<2048, 256, 0, stream>>>(embed, Wih_f, Wih_b, Whh_f, Whh_b,
                                     bih_f, bhh_f, bih_b, bhh_b,
                                     ebf, wix, whb, bsum);
    lstm_f<<<256, 512, 0, stream>>>(x, ebf, wix, whb, bsum, h0, c0, Wout,
                                    fpF, fpB);
    crf_k<<<BB, 128, 0, stream>>>(fpF, fpB, bout, y, trans, (float*)d_out);
}